// Round 1
// baseline (863.119 us; speedup 1.0000x reference)
//
#include <hip/hip_runtime.h>
#include <hip/hip_bf16.h>

#define NHITS   16384
#define NEDGES  262144
#define NGROUPS 512
#define HID     128
#define LAYERS  3
#define FFND    512

// ---------------- CSR build (edges bucketed by dst) ----------------

__global__ void count_kernel(const int* __restrict__ dst, int* __restrict__ cnt) {
    int e = blockIdx.x * 256 + threadIdx.x;
    if (e < NEDGES) atomicAdd(&cnt[dst[e]], 1);
}

__global__ __launch_bounds__(256) void scan_kernel(const int* __restrict__ cnt,
                                                   int* __restrict__ offs) {
    __shared__ int buf0[256], buf1[256];
    int t = threadIdx.x;
    int base = t * 64;
    int s = 0;
    for (int j = 0; j < 64; ++j) s += cnt[base + j];
    buf0[t] = s;
    __syncthreads();
    int* src_ = buf0; int* dst_ = buf1;
    for (int off = 1; off < 256; off <<= 1) {
        int v = src_[t];
        if (t >= off) v += src_[t - off];
        dst_[t] = v;
        __syncthreads();
        int* tmp = src_; src_ = dst_; dst_ = tmp;
    }
    int incl = src_[t];          // inclusive scan of per-thread partials
    int run = incl - s;          // exclusive start for this chunk
    for (int j = 0; j < 64; ++j) { offs[base + j] = run; run += cnt[base + j]; }
    if (t == 255) offs[NHITS] = incl;
}

__global__ void scatter_kernel(const int* __restrict__ dst, const int* __restrict__ offs,
                               int* __restrict__ cur, int* __restrict__ perm) {
    int e = blockIdx.x * 256 + threadIdx.x;
    if (e >= NEDGES) return;
    int d = dst[e];
    int pos = offs[d] + atomicAdd(&cur[d], 1);
    perm[pos] = e;
}

// ---------------- embed: h = x @ W(25x128) + b ----------------

__global__ void embed_kernel(const float* __restrict__ x, const float* __restrict__ W,
                             const float* __restrict__ b, float* __restrict__ h) {
    int i = blockIdx.x, c = threadIdx.x;   // 128 threads
    __shared__ float xs[25];
    if (c < 25) xs[c] = x[i * 25 + c];
    __syncthreads();
    float s = b[c];
#pragma unroll
    for (int k = 0; k < 25; ++k) s += xs[k] * W[k * HID + c];
    h[(size_t)i * HID + c] = s;
}

// ---------------- generic fp32 GEMM: C(MxN) = A(MxK) @ B(KxN) + bias ----------------
// 64x64 tile, 256 threads, 4x4 per thread, K-step 16. M%64==0, N%64==0, K%16==0.

__global__ __launch_bounds__(256) void gemm64(const float* __restrict__ A,
                                              const float* __restrict__ B,
                                              const float* __restrict__ bias,
                                              float* __restrict__ C,
                                              int M, int N, int K, int relu) {
    __shared__ float As[16][64];
    __shared__ float Bs[16][64];
    const int tx = threadIdx.x, ty = threadIdx.y;
    const int t = ty * 16 + tx;
    const int row0 = blockIdx.y * 64;
    const int col0 = blockIdx.x * 64;
    const int am = t >> 2;            // 0..63
    const int ak = (t & 3) * 4;       // 0,4,8,12
    const int bk = t >> 4;            // 0..15
    const int bn = (t & 15) * 4;      // 0..60
    float acc[4][4] = {};
    for (int k0 = 0; k0 < K; k0 += 16) {
        float4 av = *(const float4*)(A + (size_t)(row0 + am) * K + k0 + ak);
        As[ak + 0][am] = av.x; As[ak + 1][am] = av.y;
        As[ak + 2][am] = av.z; As[ak + 3][am] = av.w;
        float4 bv = *(const float4*)(B + (size_t)(k0 + bk) * N + col0 + bn);
        *(float4*)&Bs[bk][bn] = bv;
        __syncthreads();
#pragma unroll
        for (int kk = 0; kk < 16; ++kk) {
            float4 a = *(const float4*)&As[kk][ty * 4];
            float4 b = *(const float4*)&Bs[kk][tx * 4];
            acc[0][0] += a.x * b.x; acc[0][1] += a.x * b.y; acc[0][2] += a.x * b.z; acc[0][3] += a.x * b.w;
            acc[1][0] += a.y * b.x; acc[1][1] += a.y * b.y; acc[1][2] += a.y * b.z; acc[1][3] += a.y * b.w;
            acc[2][0] += a.z * b.x; acc[2][1] += a.z * b.y; acc[2][2] += a.z * b.z; acc[2][3] += a.z * b.w;
            acc[3][0] += a.w * b.x; acc[3][1] += a.w * b.y; acc[3][2] += a.w * b.z; acc[3][3] += a.w * b.w;
        }
        __syncthreads();
    }
    float4 bb = make_float4(0.f, 0.f, 0.f, 0.f);
    if (bias) bb = *(const float4*)(bias + col0 + tx * 4);
#pragma unroll
    for (int i = 0; i < 4; ++i) {
        int r = row0 + ty * 4 + i;
        float4 o;
        o.x = acc[i][0] + bb.x; o.y = acc[i][1] + bb.y;
        o.z = acc[i][2] + bb.z; o.w = acc[i][3] + bb.w;
        if (relu) {
            o.x = fmaxf(o.x, 0.f); o.y = fmaxf(o.y, 0.f);
            o.z = fmaxf(o.z, 0.f); o.w = fmaxf(o.w, 0.f);
        }
        *(float4*)(C + (size_t)r * N + col0 + tx * 4) = o;
    }
}

// ---------------- edge attention, flash-style, one wave per dst node ----------------

__global__ __launch_bounds__(64) void attn_kernel(const float* __restrict__ qkv,
                                                  const float* __restrict__ ea,
                                                  const int* __restrict__ src,
                                                  const int* __restrict__ perm,
                                                  const int* __restrict__ offs,
                                                  const float* __restrict__ We,
                                                  const float* __restrict__ be,
                                                  float* __restrict__ attn) {
    int i = blockIdx.x;
    int lane = threadIdx.x;   // 64
    __shared__ float WeS[5 * 128];
    __shared__ float beS[128];
    for (int idx = lane; idx < 5 * 128; idx += 64) WeS[idx] = We[idx];
    beS[lane] = be[lane];
    beS[lane + 64] = be[lane + 64];
    __syncthreads();
    const int c0 = lane * 2, c1 = lane * 2 + 1;
    const float* qrow = qkv + (size_t)i * 384;
    float q0 = qrow[c0], q1 = qrow[c1];
    float m = -INFINITY, ssum = 0.f, acc0 = 0.f, acc1 = 0.f;
    int beg = offs[i], end = offs[i + 1];
    const float scale = 0.17677669529663687f;   // 1/sqrt(32)
    for (int p = beg; p < end; ++p) {
        int e = perm[p];
        int s = src[e];
        float a0 = ea[(size_t)e * 5 + 0], a1 = ea[(size_t)e * 5 + 1],
              a2 = ea[(size_t)e * 5 + 2], a3 = ea[(size_t)e * 5 + 3],
              a4 = ea[(size_t)e * 5 + 4];
        float e0 = beS[c0] + a0 * WeS[0 * 128 + c0] + a1 * WeS[1 * 128 + c0]
                 + a2 * WeS[2 * 128 + c0] + a3 * WeS[3 * 128 + c0] + a4 * WeS[4 * 128 + c0];
        float e1 = beS[c1] + a0 * WeS[0 * 128 + c1] + a1 * WeS[1 * 128 + c1]
                 + a2 * WeS[2 * 128 + c1] + a3 * WeS[3 * 128 + c1] + a4 * WeS[4 * 128 + c1];
        const float* srow = qkv + (size_t)s * 384;
        float k0 = srow[128 + c0] + e0, k1 = srow[128 + c1] + e1;
        float part = q0 * k0 + q1 * k1;
        part += __shfl_xor(part, 1, 16);
        part += __shfl_xor(part, 2, 16);
        part += __shfl_xor(part, 4, 16);
        part += __shfl_xor(part, 8, 16);
        float logit = part * scale;
        float nm = fmaxf(m, logit);
        float alpha = __expf(m - nm);    // 0 on first edge (m = -inf)
        float pe = __expf(logit - nm);
        float v0 = srow[256 + c0] + e0, v1 = srow[256 + c1] + e1;
        ssum = ssum * alpha + pe;
        acc0 = acc0 * alpha + pe * v0;
        acc1 = acc1 * alpha + pe * v1;
        m = nm;
    }
    float inv = 1.f / fmaxf(ssum, 1e-9f);
    attn[(size_t)i * HID + c0] = acc0 * inv;
    attn[(size_t)i * HID + c1] = acc1 * inv;
}

// ---------------- residual + LayerNorm, in-place on h ----------------

__global__ __launch_bounds__(128) void ln_res_kernel(float* __restrict__ h,
                                                     const float* __restrict__ d,
                                                     const float* __restrict__ g,
                                                     const float* __restrict__ b) {
    int i = blockIdx.x, c = threadIdx.x;   // 128
    __shared__ float red[128];
    __shared__ float sh_mu, sh_rstd;
    float v = h[(size_t)i * HID + c] + d[(size_t)i * HID + c];
    red[c] = v;
    __syncthreads();
    for (int s = 64; s > 0; s >>= 1) {
        if (c < s) red[c] += red[c + s];
        __syncthreads();
    }
    if (c == 0) sh_mu = red[0] * (1.f / HID);
    __syncthreads();
    float vm = v - sh_mu;
    red[c] = vm * vm;
    __syncthreads();
    for (int s = 64; s > 0; s >>= 1) {
        if (c < s) red[c] += red[c + s];
        __syncthreads();
    }
    if (c == 0) sh_rstd = rsqrtf(red[0] * (1.f / HID) + 1e-5f);
    __syncthreads();
    h[(size_t)i * HID + c] = vm * sh_rstd * g[c] + b[c];
}

// ---------------- pooling ----------------

__device__ __forceinline__ unsigned flipf(float f) {
    unsigned u = __float_as_uint(f);
    return (u & 0x80000000u) ? ~u : (u | 0x80000000u);
}
__device__ __forceinline__ float unflipf(unsigned u) {
    return __uint_as_float((u & 0x80000000u) ? (u & 0x7FFFFFFFu) : ~u);
}

__global__ void initmax_kernel(unsigned* __restrict__ gmax) {
    int idx = blockIdx.x * 256 + threadIdx.x;
    if (idx < NGROUPS * HID) gmax[idx] = 0x007FFFFFu;   // flipf(-inf)
}

__global__ __launch_bounds__(128) void pool_kernel(const float* __restrict__ h,
                                                   const float* __restrict__ x,
                                                   const int* __restrict__ gidx,
                                                   unsigned* __restrict__ gmax,
                                                   float* __restrict__ sumx,
                                                   float* __restrict__ sumy,
                                                   float* __restrict__ cnts) {
    int i = blockIdx.x, c = threadIdx.x;   // 128
    int g = gidx[i];
    float hv = h[(size_t)i * HID + c];
    atomicMax(&gmax[g * HID + c], flipf(hv));
    int view = (int)x[i * 25 + 3];
    if (view == 0) {
        atomicAdd(&sumx[g * HID + c], hv);
        if (c == 0) atomicAdd(&cnts[NGROUPS + g], 1.f);
    } else if (view == 1) {
        atomicAdd(&sumy[g * HID + c], hv);
        if (c == 0) atomicAdd(&cnts[2 * NGROUPS + g], 1.f);
    }
    if (c == 0) atomicAdd(&cnts[g], 1.f);
}

__global__ __launch_bounds__(128) void ge_kernel(const float* __restrict__ sumx,
                                                 const float* __restrict__ sumy,
                                                 const float* __restrict__ cnts,
                                                 const unsigned* __restrict__ gmax,
                                                 float* __restrict__ ge) {
    int g = blockIdx.x, c = threadIdx.x;   // 128
    float ca = cnts[g];
    float cx = cnts[NGROUPS + g], cy = cnts[2 * NGROUPS + g];
    float gm = unflipf(gmax[g * HID + c]);
    gm = (ca > 0.f) ? gm : 0.f;
    float px = sumx[g * HID + c] / fmaxf(cx, 1.f);
    float py = sumy[g * HID + c] / fmaxf(cy, 1.f);
    float hx = (cx > 0.f) ? 1.f : 0.f, hy = (cy > 0.f) ? 1.f : 0.f;
    float sf = px * hx + py * hy;
    float valid = fmaxf(hx + hy, 1.f);
    ge[g * 256 + c] = sf / valid;
    ge[g * 256 + 128 + c] = gm;
}

// ---------------- pairwise affinity ----------------
// S[i][j] = sum_k relu(A[i][k] + B[j][k]) * W2[k] + b2

__global__ __launch_bounds__(256) void score_kernel(const float* __restrict__ A,
                                                    const float* __restrict__ Bm,
                                                    const float* __restrict__ W2,
                                                    const float* __restrict__ b2,
                                                    float* __restrict__ S) {
    __shared__ float At[16][128], Bt[16][128], w2s[128];
    int tx = threadIdx.x, ty = threadIdx.y;
    int t = ty * 16 + tx;
    int i0 = blockIdx.y * 16, j0 = blockIdx.x * 16;
    for (int e = t * 4; e < 16 * 128; e += 1024) {
        int r = e >> 7, c = e & 127;
        *(float4*)&At[r][c] = *(const float4*)&A[(size_t)(i0 + r) * HID + c];
        *(float4*)&Bt[r][c] = *(const float4*)&Bm[(size_t)(j0 + r) * HID + c];
    }
    if (t < 128) w2s[t] = W2[t];
    __syncthreads();
    float s = 0.f;
#pragma unroll 8
    for (int k = 0; k < 128; ++k)
        s += fmaxf(At[ty][k] + Bt[tx][k], 0.f) * w2s[k];
    S[(size_t)(i0 + ty) * NGROUPS + j0 + tx] = s + b2[0];
}

__global__ void final_kernel(const float* __restrict__ S, const int* __restrict__ ev,
                             float* __restrict__ out) {
    int idx = blockIdx.x * 256 + threadIdx.x;   // 262144 total
    int i = idx >> 9, j = idx & 511;
    float z = 0.5f * (S[(size_t)i * NGROUPS + j] + S[(size_t)j * NGROUPS + i]);
    float sg = 1.f / (1.f + __expf(-z));
    out[idx] = (ev[i] == ev[j]) ? sg : 0.f;
}

// ---------------- launch ----------------

extern "C" void kernel_launch(void* const* d_in, const int* in_sizes, int n_in,
                              void* d_out, int out_size, void* d_ws, size_t ws_size,
                              hipStream_t stream) {
    const float* x    = (const float*)d_in[0];
    const int* eidx   = (const int*)d_in[1];
    const float* ea   = (const float*)d_in[2];
    const int* gidx   = (const int*)d_in[3];
    const int* ev     = (const int*)d_in[4];
    const float* embW = (const float*)d_in[5];
    const float* embB = (const float*)d_in[6];
    const float* Wqkv = (const float*)d_in[7];
    const float* bqkv = (const float*)d_in[8];
    const float* We   = (const float*)d_in[9];
    const float* be   = (const float*)d_in[10];
    const float* Wo   = (const float*)d_in[11];
    const float* bo   = (const float*)d_in[12];
    const float* ln1g = (const float*)d_in[13];
    const float* ln1b = (const float*)d_in[14];
    const float* W1   = (const float*)d_in[15];
    const float* b1   = (const float*)d_in[16];
    const float* W2   = (const float*)d_in[17];
    const float* b2   = (const float*)d_in[18];
    const float* ln2g = (const float*)d_in[19];
    const float* ln2b = (const float*)d_in[20];
    const float* affW1 = (const float*)d_in[21];
    const float* affb1 = (const float*)d_in[22];
    const float* affW2 = (const float*)d_in[23];
    const float* affb2 = (const float*)d_in[24];

    const int* src = eidx;
    const int* dst = eidx + NEDGES;

    float* ws = (float*)d_ws;
    float* h    = ws;                        // 16384*128
    float* qkv  = h + (size_t)NHITS * HID;   // 16384*384
    float* attn = qkv + (size_t)NHITS * 384; // 16384*128
    float* tmp  = attn + (size_t)NHITS * HID;// 16384*128
    float* mid  = tmp + (size_t)NHITS * HID; // 16384*512
    float* ge   = mid + (size_t)NHITS * FFND;      // 512*256
    float* Aaff = ge + NGROUPS * 256;              // 512*128
    float* Baff = Aaff + NGROUPS * HID;            // 512*128
    float* S    = Baff + NGROUPS * HID;            // 512*512
    float* sumx = S + NGROUPS * NGROUPS;           // 512*128
    float* sumy = sumx + NGROUPS * HID;            // 512*128
    float* cnts = sumy + NGROUPS * HID;            // 3*512
    unsigned* gmax = (unsigned*)(cnts + 3 * NGROUPS);   // 512*128
    int* cnt  = (int*)(gmax + NGROUPS * HID);      // 16384
    int* offs = cnt + NHITS;                       // 16385
    int* cur  = offs + NHITS + 1;                  // 16384
    int* perm = cur + NHITS;                       // 262144

    // --- CSR build (dst buckets; identical for all layers) ---
    hipMemsetAsync(cnt, 0, NHITS * sizeof(int), stream);
    hipMemsetAsync(cur, 0, NHITS * sizeof(int), stream);
    count_kernel<<<NEDGES / 256, 256, 0, stream>>>(dst, cnt);
    scan_kernel<<<1, 256, 0, stream>>>(cnt, offs);
    scatter_kernel<<<NEDGES / 256, 256, 0, stream>>>(dst, offs, cur, perm);

    // --- embed ---
    embed_kernel<<<NHITS, 128, 0, stream>>>(x, embW, embB, h);

    // --- transformer layers ---
    for (int l = 0; l < LAYERS; ++l) {
        gemm64<<<dim3(384 / 64, NHITS / 64), dim3(16, 16), 0, stream>>>(
            h, Wqkv + (size_t)l * HID * 384, bqkv + l * 384, qkv, NHITS, 384, HID, 0);
        attn_kernel<<<NHITS, 64, 0, stream>>>(qkv, ea, src, perm, offs,
                                              We + (size_t)l * 5 * HID, be + l * HID, attn);
        gemm64<<<dim3(HID / 64, NHITS / 64), dim3(16, 16), 0, stream>>>(
            attn, Wo + (size_t)l * HID * HID, bo + l * HID, tmp, NHITS, HID, HID, 0);
        ln_res_kernel<<<NHITS, 128, 0, stream>>>(h, tmp, ln1g + l * HID, ln1b + l * HID);
        gemm64<<<dim3(FFND / 64, NHITS / 64), dim3(16, 16), 0, stream>>>(
            h, W1 + (size_t)l * HID * FFND, b1 + l * FFND, mid, NHITS, FFND, HID, 1);
        gemm64<<<dim3(HID / 64, NHITS / 64), dim3(16, 16), 0, stream>>>(
            mid, W2 + (size_t)l * FFND * HID, b2 + l * HID, tmp, NHITS, HID, FFND, 0);
        ln_res_kernel<<<NHITS, 128, 0, stream>>>(h, tmp, ln2g + l * HID, ln2b + l * HID);
    }

    // --- pooling ---
    hipMemsetAsync(sumx, 0, NGROUPS * HID * sizeof(float), stream);
    hipMemsetAsync(sumy, 0, NGROUPS * HID * sizeof(float), stream);
    hipMemsetAsync(cnts, 0, 3 * NGROUPS * sizeof(float), stream);
    initmax_kernel<<<(NGROUPS * HID + 255) / 256, 256, 0, stream>>>(gmax);
    pool_kernel<<<NHITS, 128, 0, stream>>>(h, x, gidx, gmax, sumx, sumy, cnts);
    ge_kernel<<<NGROUPS, 128, 0, stream>>>(sumx, sumy, cnts, gmax, ge);

    // --- affinity head ---
    const float* W1a = affW1;               // rows 0..255
    const float* W1b = affW1 + 256 * HID;   // rows 256..511
    gemm64<<<dim3(HID / 64, NGROUPS / 64), dim3(16, 16), 0, stream>>>(
        ge, W1a, affb1, Aaff, NGROUPS, HID, 256, 0);
    gemm64<<<dim3(HID / 64, NGROUPS / 64), dim3(16, 16), 0, stream>>>(
        ge, W1b, nullptr, Baff, NGROUPS, HID, 256, 0);
    score_kernel<<<dim3(NGROUPS / 16, NGROUPS / 16), dim3(16, 16), 0, stream>>>(
        Aaff, Baff, affW2, affb2, S);
    final_kernel<<<NGROUPS * NGROUPS / 256, 256, 0, stream>>>(S, ev, (float*)d_out);
}

// Round 2
// 532.481 us; speedup vs baseline: 1.6209x; 1.6209x over previous
//
#include <hip/hip_runtime.h>
#include <hip/hip_bf16.h>

#define NHITS   16384
#define NEDGES  262144
#define NGROUPS 512
#define HID     128
#define LAYERS  3
#define FFND    512

typedef __attribute__((ext_vector_type(8))) short bf16x8;
typedef __attribute__((ext_vector_type(4))) float floatx4;

__device__ __forceinline__ float bf2f(ushort u) {
    return __uint_as_float(((unsigned)u) << 16);
}
__device__ __forceinline__ ushort f2bf(float f) {
    unsigned u = __float_as_uint(f);
    unsigned r = (u + 0x7FFFu + ((u >> 16) & 1u)) >> 16;
    return (ushort)r;
}

// ---------------- weight convert + transpose: Wt[n*K+k] = bf16(W[k*N+n]) ----------------

__global__ void convw_kernel(const float* __restrict__ W, ushort* __restrict__ Wt,
                             int K, int N) {
    int idx = blockIdx.x * 256 + threadIdx.x;
    if (idx >= K * N) return;
    int n = idx / K, k = idx - n * K;
    Wt[idx] = f2bf(W[k * N + n]);
}

// ---------------- CSR build (edges bucketed by dst) ----------------

__global__ void count_kernel(const int* __restrict__ dst, int* __restrict__ cnt) {
    int e = blockIdx.x * 256 + threadIdx.x;
    if (e < NEDGES) atomicAdd(&cnt[dst[e]], 1);
}

__global__ __launch_bounds__(256) void scan_kernel(const int* __restrict__ cnt,
                                                   int* __restrict__ offs) {
    __shared__ int buf0[256], buf1[256];
    int t = threadIdx.x;
    int base = t * 64;
    int s = 0;
    for (int j = 0; j < 64; ++j) s += cnt[base + j];
    buf0[t] = s;
    __syncthreads();
    int* src_ = buf0; int* dst_ = buf1;
    for (int off = 1; off < 256; off <<= 1) {
        int v = src_[t];
        if (t >= off) v += src_[t - off];
        dst_[t] = v;
        __syncthreads();
        int* tmp = src_; src_ = dst_; dst_ = tmp;
    }
    int incl = src_[t];
    int run = incl - s;
    for (int j = 0; j < 64; ++j) { offs[base + j] = run; run += cnt[base + j]; }
    if (t == 255) offs[NHITS] = incl;
}

// scatter: also pack src + edge_attr by CSR position (sequential reads in attn)
__global__ void scatter_kernel(const int* __restrict__ src, const int* __restrict__ dst,
                               const float* __restrict__ ea,
                               const int* __restrict__ offs,
                               int* __restrict__ cur,
                               int* __restrict__ ps, float* __restrict__ pea) {
    int e = blockIdx.x * 256 + threadIdx.x;
    if (e >= NEDGES) return;
    int d = dst[e];
    int pos = offs[d] + atomicAdd(&cur[d], 1);
    ps[pos] = src[e];
#pragma unroll
    for (int j = 0; j < 5; ++j) pea[(size_t)pos * 5 + j] = ea[(size_t)e * 5 + j];
}

// ---------------- embed: h = x @ W(25x128) + b ; writes fp32 h and bf16 hb ----------------

__global__ void embed_kernel(const float* __restrict__ x, const float* __restrict__ W,
                             const float* __restrict__ b, float* __restrict__ h,
                             ushort* __restrict__ hb) {
    int i = blockIdx.x, c = threadIdx.x;   // 128 threads
    __shared__ float xs[25];
    if (c < 25) xs[c] = x[i * 25 + c];
    __syncthreads();
    float s = b[c];
#pragma unroll
    for (int k = 0; k < 25; ++k) s += xs[k] * W[k * HID + c];
    h[(size_t)i * HID + c] = s;
    hb[(size_t)i * HID + c] = f2bf(s);
}

// ---------------- bf16 MFMA GEMM: C(MxN) = A(MxK) @ Bt(NxK)^T + bias ----------------
// 128x128 tile, 256 threads = 4 waves (2x2), each wave 64x64 = 4x4 MFMA 16x16x32.
// LDS stride padded 32->40 ushorts (80B): lane bank stride 20 -> 2-way (free).

#define LSTR 40

__global__ __launch_bounds__(256) void gemm_mfma(const ushort* __restrict__ A,
                                                 const ushort* __restrict__ Bt,
                                                 const float* __restrict__ bias,
                                                 ushort* __restrict__ C,
                                                 int M, int N, int K, int relu) {
    __shared__ ushort As[128 * LSTR];
    __shared__ ushort Bs[128 * LSTR];
    const int t = threadIdx.x;
    const int lane = t & 63;
    const int w = t >> 6;
    const int wr = w >> 1, wc = w & 1;
    const int lm = lane & 15, q = lane >> 4;
    const int row0 = blockIdx.y * 128;
    const int col0 = blockIdx.x * 128;

    floatx4 acc[4][4] = {};

    for (int k0 = 0; k0 < K; k0 += 32) {
#pragma unroll
        for (int i = 0; i < 2; ++i) {
            int seg = t + i * 256;              // 0..511
            int row = seg >> 2, c8 = (seg & 3) * 8;
            *(float4*)&As[row * LSTR + c8] =
                *(const float4*)(A + (size_t)(row0 + row) * K + k0 + c8);
            *(float4*)&Bs[row * LSTR + c8] =
                *(const float4*)(Bt + (size_t)(col0 + row) * K + k0 + c8);
        }
        __syncthreads();
        bf16x8 af[4], bf[4];
#pragma unroll
        for (int it = 0; it < 4; ++it)
            af[it] = *(const bf16x8*)&As[(wr * 64 + it * 16 + lm) * LSTR + q * 8];
#pragma unroll
        for (int jt = 0; jt < 4; ++jt)
            bf[jt] = *(const bf16x8*)&Bs[(wc * 64 + jt * 16 + lm) * LSTR + q * 8];
#pragma unroll
        for (int it = 0; it < 4; ++it)
#pragma unroll
            for (int jt = 0; jt < 4; ++jt)
                acc[it][jt] = __builtin_amdgcn_mfma_f32_16x16x32_bf16(
                    af[it], bf[jt], acc[it][jt], 0, 0, 0);
        __syncthreads();
    }

#pragma unroll
    for (int jt = 0; jt < 4; ++jt) {
        int col = col0 + wc * 64 + jt * 16 + lm;
        float bb = bias ? bias[col] : 0.f;
#pragma unroll
        for (int it = 0; it < 4; ++it) {
#pragma unroll
            for (int r = 0; r < 4; ++r) {
                int row = row0 + wr * 64 + it * 16 + q * 4 + r;
                float o = acc[it][jt][r] + bb;
                if (relu) o = fmaxf(o, 0.f);
                C[(size_t)row * N + col] = f2bf(o);
            }
        }
    }
}

// ---------------- edge attention, flash-style, one wave per dst node, bf16 qkv ----------------

__global__ __launch_bounds__(64) void attn_kernel(const ushort* __restrict__ qkv,
                                                  const int* __restrict__ ps,
                                                  const float* __restrict__ pea,
                                                  const int* __restrict__ offs,
                                                  const float* __restrict__ We,
                                                  const float* __restrict__ be,
                                                  ushort* __restrict__ attnb) {
    int i = blockIdx.x;
    int lane = threadIdx.x;   // 64
    __shared__ float WeS[5 * 128];
    __shared__ float beS[128];
    for (int idx = lane; idx < 5 * 128; idx += 64) WeS[idx] = We[idx];
    beS[lane] = be[lane];
    beS[lane + 64] = be[lane + 64];
    __syncthreads();
    const int c0 = lane * 2, c1 = lane * 2 + 1;
    const ushort* qrow = qkv + (size_t)i * 384;
    float q0 = bf2f(qrow[c0]), q1 = bf2f(qrow[c1]);
    float m = -INFINITY, ssum = 0.f, acc0 = 0.f, acc1 = 0.f;
    int beg = offs[i], end = offs[i + 1];
    const float scale = 0.17677669529663687f;   // 1/sqrt(32)
    for (int p = beg; p < end; ++p) {
        int s = ps[p];
        float a0 = pea[(size_t)p * 5 + 0], a1 = pea[(size_t)p * 5 + 1],
              a2 = pea[(size_t)p * 5 + 2], a3 = pea[(size_t)p * 5 + 3],
              a4 = pea[(size_t)p * 5 + 4];
        float e0 = beS[c0] + a0 * WeS[0 * 128 + c0] + a1 * WeS[1 * 128 + c0]
                 + a2 * WeS[2 * 128 + c0] + a3 * WeS[3 * 128 + c0] + a4 * WeS[4 * 128 + c0];
        float e1 = beS[c1] + a0 * WeS[0 * 128 + c1] + a1 * WeS[1 * 128 + c1]
                 + a2 * WeS[2 * 128 + c1] + a3 * WeS[3 * 128 + c1] + a4 * WeS[4 * 128 + c1];
        const ushort* srow = qkv + (size_t)s * 384;
        float k0 = bf2f(srow[128 + c0]) + e0, k1 = bf2f(srow[128 + c1]) + e1;
        float part = q0 * k0 + q1 * k1;
        part += __shfl_xor(part, 1, 16);
        part += __shfl_xor(part, 2, 16);
        part += __shfl_xor(part, 4, 16);
        part += __shfl_xor(part, 8, 16);
        float logit = part * scale;
        float nm = fmaxf(m, logit);
        float alpha = __expf(m - nm);    // 0 on first edge (m = -inf)
        float pe = __expf(logit - nm);
        float v0 = bf2f(srow[256 + c0]) + e0, v1 = bf2f(srow[256 + c1]) + e1;
        ssum = ssum * alpha + pe;
        acc0 = acc0 * alpha + pe * v0;
        acc1 = acc1 * alpha + pe * v1;
        m = nm;
    }
    float inv = 1.f / fmaxf(ssum, 1e-9f);
    attnb[(size_t)i * HID + c0] = f2bf(acc0 * inv);
    attnb[(size_t)i * HID + c1] = f2bf(acc1 * inv);
}

// ---------------- residual + LayerNorm (one wave), h fp32 in/out, hb bf16 out ----------------

__global__ __launch_bounds__(64) void ln_res_kernel(float* __restrict__ h,
                                                    const ushort* __restrict__ d,
                                                    const float* __restrict__ g,
                                                    const float* __restrict__ b,
                                                    ushort* __restrict__ hb) {
    int i = blockIdx.x, l = threadIdx.x;
    int c0 = 2 * l, c1 = c0 + 1;
    size_t base = (size_t)i * HID;
    float v0 = h[base + c0] + bf2f(d[base + c0]);
    float v1 = h[base + c1] + bf2f(d[base + c1]);
    float s = v0 + v1;
#pragma unroll
    for (int off = 32; off; off >>= 1) s += __shfl_xor(s, off);
    float mu = s * (1.f / HID);
    float d0 = v0 - mu, d1 = v1 - mu;
    float vs = d0 * d0 + d1 * d1;
#pragma unroll
    for (int off = 32; off; off >>= 1) vs += __shfl_xor(vs, off);
    float rstd = rsqrtf(vs * (1.f / HID) + 1e-5f);
    float o0 = d0 * rstd * g[c0] + b[c0];
    float o1 = d1 * rstd * g[c1] + b[c1];
    h[base + c0] = o0; h[base + c1] = o1;
    hb[base + c0] = f2bf(o0); hb[base + c1] = f2bf(o1);
}

// ---------------- pooling ----------------

__device__ __forceinline__ unsigned flipf(float f) {
    unsigned u = __float_as_uint(f);
    return (u & 0x80000000u) ? ~u : (u | 0x80000000u);
}
__device__ __forceinline__ float unflipf(unsigned u) {
    return __uint_as_float((u & 0x80000000u) ? (u & 0x7FFFFFFFu) : ~u);
}

__global__ void initmax_kernel(unsigned* __restrict__ gmax) {
    int idx = blockIdx.x * 256 + threadIdx.x;
    if (idx < NGROUPS * HID) gmax[idx] = 0x007FFFFFu;   // flipf(-inf)
}

__global__ __launch_bounds__(128) void pool_kernel(const float* __restrict__ h,
                                                   const float* __restrict__ x,
                                                   const int* __restrict__ gidx,
                                                   unsigned* __restrict__ gmax,
                                                   float* __restrict__ sumx,
                                                   float* __restrict__ sumy,
                                                   float* __restrict__ cnts) {
    int i = blockIdx.x, c = threadIdx.x;   // 128
    int g = gidx[i];
    float hv = h[(size_t)i * HID + c];
    atomicMax(&gmax[g * HID + c], flipf(hv));
    int view = (int)x[i * 25 + 3];
    if (view == 0) {
        atomicAdd(&sumx[g * HID + c], hv);
        if (c == 0) atomicAdd(&cnts[NGROUPS + g], 1.f);
    } else if (view == 1) {
        atomicAdd(&sumy[g * HID + c], hv);
        if (c == 0) atomicAdd(&cnts[2 * NGROUPS + g], 1.f);
    }
    if (c == 0) atomicAdd(&cnts[g], 1.f);
}

__global__ __launch_bounds__(128) void ge_kernel(const float* __restrict__ sumx,
                                                 const float* __restrict__ sumy,
                                                 const float* __restrict__ cnts,
                                                 const unsigned* __restrict__ gmax,
                                                 ushort* __restrict__ geb) {
    int g = blockIdx.x, c = threadIdx.x;   // 128
    float ca = cnts[g];
    float cx = cnts[NGROUPS + g], cy = cnts[2 * NGROUPS + g];
    float gm = unflipf(gmax[g * HID + c]);
    gm = (ca > 0.f) ? gm : 0.f;
    float px = sumx[g * HID + c] / fmaxf(cx, 1.f);
    float py = sumy[g * HID + c] / fmaxf(cy, 1.f);
    float hx = (cx > 0.f) ? 1.f : 0.f, hy = (cy > 0.f) ? 1.f : 0.f;
    float sf = px * hx + py * hy;
    float valid = fmaxf(hx + hy, 1.f);
    geb[g * 256 + c] = f2bf(sf / valid);
    geb[g * 256 + 128 + c] = f2bf(gm);
}

// ---------------- pairwise affinity ----------------
// S[i][j] = sum_k relu(A[i][k] + B[j][k]) * W2[k] + b2

__global__ __launch_bounds__(256) void score_kernel(const ushort* __restrict__ A,
                                                    const ushort* __restrict__ Bm,
                                                    const float* __restrict__ W2,
                                                    const float* __restrict__ b2,
                                                    float* __restrict__ S) {
    __shared__ float At[16][128], Bt[16][128], w2s[128];
    int tx = threadIdx.x, ty = threadIdx.y;
    int t = ty * 16 + tx;
    int i0 = blockIdx.y * 16, j0 = blockIdx.x * 16;
    for (int e = t * 8; e < 16 * 128; e += 2048) {
        int r = e >> 7, c = e & 127;
#pragma unroll
        for (int j = 0; j < 8; ++j) {
            At[r][c + j] = bf2f(A[(size_t)(i0 + r) * HID + c + j]);
            Bt[r][c + j] = bf2f(Bm[(size_t)(j0 + r) * HID + c + j]);
        }
    }
    if (t < 128) w2s[t] = W2[t];
    __syncthreads();
    float s = 0.f;
#pragma unroll 8
    for (int k = 0; k < 128; ++k)
        s += fmaxf(At[ty][k] + Bt[tx][k], 0.f) * w2s[k];
    S[(size_t)(i0 + ty) * NGROUPS + j0 + tx] = s + b2[0];
}

__global__ void final_kernel(const float* __restrict__ S, const int* __restrict__ ev,
                             float* __restrict__ out) {
    int idx = blockIdx.x * 256 + threadIdx.x;   // 262144 total
    int i = idx >> 9, j = idx & 511;
    float z = 0.5f * (S[(size_t)i * NGROUPS + j] + S[(size_t)j * NGROUPS + i]);
    float sg = 1.f / (1.f + __expf(-z));
    out[idx] = (ev[i] == ev[j]) ? sg : 0.f;
}

// ---------------- launch ----------------

static inline char* align256(char* p) {
    return (char*)(((uintptr_t)p + 255) & ~(uintptr_t)255);
}

extern "C" void kernel_launch(void* const* d_in, const int* in_sizes, int n_in,
                              void* d_out, int out_size, void* d_ws, size_t ws_size,
                              hipStream_t stream) {
    const float* x    = (const float*)d_in[0];
    const int* eidx   = (const int*)d_in[1];
    const float* ea   = (const float*)d_in[2];
    const int* gidx   = (const int*)d_in[3];
    const int* ev     = (const int*)d_in[4];
    const float* embW = (const float*)d_in[5];
    const float* embB = (const float*)d_in[6];
    const float* Wqkv = (const float*)d_in[7];
    const float* bqkv = (const float*)d_in[8];
    const float* We   = (const float*)d_in[9];
    const float* be   = (const float*)d_in[10];
    const float* Wo   = (const float*)d_in[11];
    const float* bo   = (const float*)d_in[12];
    const float* ln1g = (const float*)d_in[13];
    const float* ln1b = (const float*)d_in[14];
    const float* W1   = (const float*)d_in[15];
    const float* b1   = (const float*)d_in[16];
    const float* W2   = (const float*)d_in[17];
    const float* b2   = (const float*)d_in[18];
    const float* ln2g = (const float*)d_in[19];
    const float* ln2b = (const float*)d_in[20];
    const float* affW1 = (const float*)d_in[21];
    const float* affb1 = (const float*)d_in[22];
    const float* affW2 = (const float*)d_in[23];
    const float* affb2 = (const float*)d_in[24];

    const int* src = eidx;
    const int* dst = eidx + NEDGES;

    char* p = (char*)d_ws;
    float* h    = (float*)p;            p += (size_t)NHITS * HID * 4;
    float* S    = (float*)p;            p += (size_t)NGROUPS * NGROUPS * 4;
    float* sumx = (float*)p;            p += (size_t)NGROUPS * HID * 4;
    float* sumy = (float*)p;            p += (size_t)NGROUPS * HID * 4;
    float* cnts = (float*)p;            p += 3 * NGROUPS * 4;
    p = align256(p);
    unsigned* gmax = (unsigned*)p;      p += (size_t)NGROUPS * HID * 4;
    float* pea  = (float*)p;            p += (size_t)NEDGES * 5 * 4;
    int* cnt    = (int*)p;              p += NHITS * 4;
    int* offs   = (int*)p;              p += (NHITS + 1) * 4;
    int* cur    = (int*)p;              p += NHITS * 4;
    int* ps     = (int*)p;              p += NEDGES * 4;
    p = align256(p);
    ushort* hb   = (ushort*)p;          p += (size_t)NHITS * HID * 2;
    ushort* qkvb = (ushort*)p;          p += (size_t)NHITS * 384 * 2;
    ushort* attnb= (ushort*)p;          p += (size_t)NHITS * HID * 2;
    ushort* tmpb = (ushort*)p;          p += (size_t)NHITS * HID * 2;
    ushort* midb = (ushort*)p;          p += (size_t)NHITS * FFND * 2;
    ushort* geb  = (ushort*)p;          p += (size_t)NGROUPS * 256 * 2;
    ushort* Aaffb= (ushort*)p;          p += (size_t)NGROUPS * HID * 2;
    ushort* Baffb= (ushort*)p;          p += (size_t)NGROUPS * HID * 2;
    p = align256(p);
    ushort* Wqkvt = (ushort*)p;         p += (size_t)LAYERS * 384 * HID * 2;
    ushort* Wot   = (ushort*)p;         p += (size_t)LAYERS * HID * HID * 2;
    ushort* W1t   = (ushort*)p;         p += (size_t)LAYERS * FFND * HID * 2;
    ushort* W2t   = (ushort*)p;         p += (size_t)LAYERS * HID * FFND * 2;
    ushort* W1at  = (ushort*)p;         p += (size_t)HID * 256 * 2;
    ushort* W1bt  = (ushort*)p;         p += (size_t)HID * 256 * 2;

    // --- weight conversion (bf16 + transpose), once per launch ---
    for (int l = 0; l < LAYERS; ++l) {
        convw_kernel<<<(HID * 384 + 255) / 256, 256, 0, stream>>>(
            Wqkv + (size_t)l * HID * 384, Wqkvt + (size_t)l * 384 * HID, HID, 384);
        convw_kernel<<<(HID * HID + 255) / 256, 256, 0, stream>>>(
            Wo + (size_t)l * HID * HID, Wot + (size_t)l * HID * HID, HID, HID);
        convw_kernel<<<(HID * FFND + 255) / 256, 256, 0, stream>>>(
            W1 + (size_t)l * HID * FFND, W1t + (size_t)l * FFND * HID, HID, FFND);
        convw_kernel<<<(FFND * HID + 255) / 256, 256, 0, stream>>>(
            W2 + (size_t)l * FFND * HID, W2t + (size_t)l * HID * FFND, FFND, HID);
    }
    convw_kernel<<<(256 * HID + 255) / 256, 256, 0, stream>>>(affW1, W1at, 256, HID);
    convw_kernel<<<(256 * HID + 255) / 256, 256, 0, stream>>>(affW1 + 256 * HID, W1bt, 256, HID);

    // --- CSR build (dst buckets; identical for all layers) ---
    hipMemsetAsync(cnt, 0, NHITS * sizeof(int), stream);
    hipMemsetAsync(cur, 0, NHITS * sizeof(int), stream);
    count_kernel<<<NEDGES / 256, 256, 0, stream>>>(dst, cnt);
    scan_kernel<<<1, 256, 0, stream>>>(cnt, offs);
    scatter_kernel<<<NEDGES / 256, 256, 0, stream>>>(src, dst, ea, offs, cur, ps, pea);

    // --- embed ---
    embed_kernel<<<NHITS, 128, 0, stream>>>(x, embW, embB, h, hb);

    // --- transformer layers ---
    for (int l = 0; l < LAYERS; ++l) {
        gemm_mfma<<<dim3(384 / 128, NHITS / 128), 256, 0, stream>>>(
            hb, Wqkvt + (size_t)l * 384 * HID, bqkv + l * 384, qkvb, NHITS, 384, HID, 0);
        attn_kernel<<<NHITS, 64, 0, stream>>>(qkvb, ps, pea, offs,
                                              We + (size_t)l * 5 * HID, be + l * HID, attnb);
        gemm_mfma<<<dim3(1, NHITS / 128), 256, 0, stream>>>(
            attnb, Wot + (size_t)l * HID * HID, bo + l * HID, tmpb, NHITS, HID, HID, 0);
        ln_res_kernel<<<NHITS, 64, 0, stream>>>(h, tmpb, ln1g + l * HID, ln1b + l * HID, hb);
        gemm_mfma<<<dim3(FFND / 128, NHITS / 128), 256, 0, stream>>>(
            hb, W1t + (size_t)l * FFND * HID, b1 + l * FFND, midb, NHITS, FFND, HID, 1);
        gemm_mfma<<<dim3(1, NHITS / 128), 256, 0, stream>>>(
            midb, W2t + (size_t)l * HID * FFND, b2 + l * HID, tmpb, NHITS, HID, FFND, 0);
        ln_res_kernel<<<NHITS, 64, 0, stream>>>(h, tmpb, ln2g + l * HID, ln2b + l * HID, hb);
    }

    // --- pooling ---
    hipMemsetAsync(sumx, 0, NGROUPS * HID * sizeof(float), stream);
    hipMemsetAsync(sumy, 0, NGROUPS * HID * sizeof(float), stream);
    hipMemsetAsync(cnts, 0, 3 * NGROUPS * sizeof(float), stream);
    initmax_kernel<<<(NGROUPS * HID + 255) / 256, 256, 0, stream>>>(gmax);
    pool_kernel<<<NHITS, 128, 0, stream>>>(h, x, gidx, gmax, sumx, sumy, cnts);
    ge_kernel<<<NGROUPS, 128, 0, stream>>>(sumx, sumy, cnts, gmax, geb);

    // --- affinity head ---
    gemm_mfma<<<dim3(1, NGROUPS / 128), 256, 0, stream>>>(
        geb, W1at, affb1, Aaffb, NGROUPS, HID, 256, 0);
    gemm_mfma<<<dim3(1, NGROUPS / 128), 256, 0, stream>>>(
        geb, W1bt, nullptr, Baffb, NGROUPS, HID, 256, 0);
    score_kernel<<<dim3(NGROUPS / 16, NGROUPS / 16), dim3(16, 16), 0, stream>>>(
        Aaffb, Baffb, affW2, affb2, S);
    final_kernel<<<NGROUPS * NGROUPS / 256, 256, 0, stream>>>(S, ev, (float*)d_out);
}

// Round 3
// 441.118 us; speedup vs baseline: 1.9567x; 1.2071x over previous
//
#include <hip/hip_runtime.h>
#include <hip/hip_bf16.h>

#define NHITS   16384
#define NEDGES  262144
#define NGROUPS 512
#define HID     128
#define LAYERS  3
#define FFND    512
#define LSTR    40

typedef __attribute__((ext_vector_type(8))) short bf16x8;
typedef __attribute__((ext_vector_type(4))) float floatx4;

__device__ __forceinline__ float bf2f(ushort u) {
    return __uint_as_float(((unsigned)u) << 16);
}
__device__ __forceinline__ ushort f2bf(float f) {
    unsigned u = __float_as_uint(f);
    unsigned r = (u + 0x7FFFu + ((u >> 16) & 1u)) >> 16;
    return (ushort)r;
}

// ---------------- batched weight transpose+convert: dst[n*K+k] = bf16(src[k*N+n]) ----------------

struct TD { const float* src; ushort* dst; int K; int N; };
struct TDs { TD d[14]; };

__global__ __launch_bounds__(256) void transpose_all(TDs tds) {
    __shared__ float lds[32][33];
    TD d = tds.d[blockIdx.y];
    int tX = d.N >> 5;
    int tiles = (d.K >> 5) * tX;
    if ((int)blockIdx.x >= tiles) return;
    int tk = blockIdx.x / tX, tn = blockIdx.x % tX;
    int k0 = tk * 32, n0 = tn * 32;
    int r = threadIdx.x >> 5, c = threadIdx.x & 31;
#pragma unroll
    for (int i = 0; i < 4; ++i)
        lds[r + i * 8][c] = d.src[(size_t)(k0 + r + i * 8) * d.N + n0 + c];
    __syncthreads();
#pragma unroll
    for (int i = 0; i < 4; ++i) {
        int n = n0 + r + i * 8;
        d.dst[(size_t)n * d.K + k0 + c] = f2bf(lds[c][r + i * 8]);
    }
}

// ---------------- CSR build: edges->dst buckets AND hits->group buckets ----------------

__global__ void count_kernel(const int* __restrict__ dst, const int* __restrict__ gidx,
                             int* __restrict__ cnt, int* __restrict__ cnt2) {
    int e = blockIdx.x * 256 + threadIdx.x;
    if (e < NEDGES) atomicAdd(&cnt[dst[e]], 1);
    if (e < NHITS) atomicAdd(&cnt2[gidx[e]], 1);
}

__global__ __launch_bounds__(256) void scan_kernel(const int* __restrict__ cnt,
                                                   int* __restrict__ offs,
                                                   const int* __restrict__ cnt2,
                                                   int* __restrict__ offs2) {
    __shared__ int buf0[256], buf1[256];
    int t = threadIdx.x;
    {   // edge scan: 16384 elems, 64/thread
        int base = t * 64, s = 0;
        for (int j = 0; j < 64; ++j) s += cnt[base + j];
        buf0[t] = s;
        __syncthreads();
        int* a = buf0; int* b = buf1;
        for (int off = 1; off < 256; off <<= 1) {
            int v = a[t];
            if (t >= off) v += a[t - off];
            b[t] = v;
            __syncthreads();
            int* tmp = a; a = b; b = tmp;
        }
        int incl = a[t], run = incl - s;
        for (int j = 0; j < 64; ++j) { offs[base + j] = run; run += cnt[base + j]; }
        if (t == 255) offs[NHITS] = incl;
        __syncthreads();
    }
    {   // group scan: 512 elems, 2/thread
        int c0 = cnt2[2 * t], c1 = cnt2[2 * t + 1];
        int s = c0 + c1;
        buf0[t] = s;
        __syncthreads();
        int* a = buf0; int* b = buf1;
        for (int off = 1; off < 256; off <<= 1) {
            int v = a[t];
            if (t >= off) v += a[t - off];
            b[t] = v;
            __syncthreads();
            int* tmp = a; a = b; b = tmp;
        }
        int incl = a[t], run = incl - s;
        offs2[2 * t] = run;
        offs2[2 * t + 1] = run + c0;
        if (t == 255) offs2[NGROUPS] = incl;
    }
}

__global__ void scatter_kernel(const int* __restrict__ src, const int* __restrict__ dst,
                               const float* __restrict__ ea, const int* __restrict__ gidx,
                               const int* __restrict__ offs, int* __restrict__ cur,
                               int* __restrict__ ps, float* __restrict__ pea,
                               const int* __restrict__ offs2, int* __restrict__ cur2,
                               int* __restrict__ hlist) {
    int e = blockIdx.x * 256 + threadIdx.x;
    if (e < NEDGES) {
        int d = dst[e];
        int pos = offs[d] + atomicAdd(&cur[d], 1);
        ps[pos] = src[e];
#pragma unroll
        for (int j = 0; j < 5; ++j) pea[(size_t)pos * 5 + j] = ea[(size_t)e * 5 + j];
    }
    if (e < NHITS) {
        int g = gidx[e];
        int pos = offs2[g] + atomicAdd(&cur2[g], 1);
        hlist[pos] = e;
    }
}

// ---------------- embed: h = x @ W(25x128) + b ----------------

__global__ void embed_kernel(const float* __restrict__ x, const float* __restrict__ W,
                             const float* __restrict__ b, float* __restrict__ h,
                             ushort* __restrict__ hb) {
    int i = blockIdx.x, c = threadIdx.x;   // 128 threads
    __shared__ float xs[25];
    if (c < 25) xs[c] = x[i * 25 + c];
    __syncthreads();
    float s = b[c];
#pragma unroll
    for (int k = 0; k < 25; ++k) s += xs[k] * W[k * HID + c];
    h[(size_t)i * HID + c] = s;
    hb[(size_t)i * HID + c] = f2bf(s);
}

// ---------------- bf16 MFMA GEMM (no LN): C(MxN) = A(MxK) @ Bt(NxK)^T + bias ----------------
// 128x128 tile, 4 waves (2x2), 4x4 MFMA 16x16x32 per wave.

__global__ __launch_bounds__(256) void gemm_mfma(const ushort* __restrict__ A,
                                                 const ushort* __restrict__ Bt,
                                                 const float* __restrict__ bias,
                                                 ushort* __restrict__ C,
                                                 int M, int N, int K, int relu) {
    __shared__ ushort As[128 * LSTR];
    __shared__ ushort Bs[128 * LSTR];
    const int t = threadIdx.x;
    const int lane = t & 63;
    const int w = t >> 6;
    const int wr = w >> 1, wc = w & 1;
    const int lm = lane & 15, q = lane >> 4;
    const int row0 = blockIdx.y * 128;
    const int col0 = blockIdx.x * 128;

    floatx4 acc[4][4] = {};

    for (int k0 = 0; k0 < K; k0 += 32) {
#pragma unroll
        for (int i = 0; i < 2; ++i) {
            int seg = t + i * 256;
            int row = seg >> 2, c8 = (seg & 3) * 8;
            *(float4*)&As[row * LSTR + c8] =
                *(const float4*)(A + (size_t)(row0 + row) * K + k0 + c8);
            *(float4*)&Bs[row * LSTR + c8] =
                *(const float4*)(Bt + (size_t)(col0 + row) * K + k0 + c8);
        }
        __syncthreads();
        bf16x8 af[4], bf[4];
#pragma unroll
        for (int it = 0; it < 4; ++it)
            af[it] = *(const bf16x8*)&As[(wr * 64 + it * 16 + lm) * LSTR + q * 8];
#pragma unroll
        for (int jt = 0; jt < 4; ++jt)
            bf[jt] = *(const bf16x8*)&Bs[(wc * 64 + jt * 16 + lm) * LSTR + q * 8];
#pragma unroll
        for (int it = 0; it < 4; ++it)
#pragma unroll
            for (int jt = 0; jt < 4; ++jt)
                acc[it][jt] = __builtin_amdgcn_mfma_f32_16x16x32_bf16(
                    af[it], bf[jt], acc[it][jt], 0, 0, 0);
        __syncthreads();
    }

#pragma unroll
    for (int jt = 0; jt < 4; ++jt) {
        int col = col0 + wc * 64 + jt * 16 + lm;
        float bb = bias ? bias[col] : 0.f;
#pragma unroll
        for (int it = 0; it < 4; ++it) {
#pragma unroll
            for (int r = 0; r < 4; ++r) {
                int row = row0 + wr * 64 + it * 16 + q * 4 + r;
                float o = acc[it][jt][r] + bb;
                if (relu) o = fmaxf(o, 0.f);
                C[(size_t)row * N + col] = f2bf(o);
            }
        }
    }
}

// ---------------- fused GEMM (N=128) + residual + LayerNorm ----------------
// 64x128 tile, 4 waves (2 row-halves x 2 col-halves), each wave 32x64.
// h (fp32 residual stream) updated in place; hb (bf16 mirror) written.

__global__ __launch_bounds__(256) void gemm_ln(const ushort* __restrict__ A,
                                               const ushort* __restrict__ Bt,
                                               const float* __restrict__ bias,
                                               const float* __restrict__ g,
                                               const float* __restrict__ b,
                                               float* __restrict__ h,
                                               ushort* __restrict__ hb,
                                               int K) {
    __shared__ ushort As[64 * LSTR];
    __shared__ ushort Bs[128 * LSTR];
    __shared__ float redS[128], redQ[128];
    const int t = threadIdx.x;
    const int lane = t & 63;
    const int w = t >> 6;
    const int wr = w >> 1, wc = w & 1;
    const int lm = lane & 15, q = lane >> 4;
    const int row0 = blockIdx.x * 64;

    floatx4 acc[2][4] = {};

    for (int k0 = 0; k0 < K; k0 += 32) {
        {
            int row = t >> 2, c8 = (t & 3) * 8;
            *(float4*)&As[row * LSTR + c8] =
                *(const float4*)(A + (size_t)(row0 + row) * K + k0 + c8);
        }
#pragma unroll
        for (int i = 0; i < 2; ++i) {
            int seg = t + i * 256;
            int row = seg >> 2, c8 = (seg & 3) * 8;
            *(float4*)&Bs[row * LSTR + c8] =
                *(const float4*)(Bt + (size_t)row * K + k0 + c8);
        }
        __syncthreads();
        bf16x8 af[2], bf[4];
#pragma unroll
        for (int it = 0; it < 2; ++it)
            af[it] = *(const bf16x8*)&As[(wr * 32 + it * 16 + lm) * LSTR + q * 8];
#pragma unroll
        for (int jt = 0; jt < 4; ++jt)
            bf[jt] = *(const bf16x8*)&Bs[(wc * 64 + jt * 16 + lm) * LSTR + q * 8];
#pragma unroll
        for (int it = 0; it < 2; ++it)
#pragma unroll
            for (int jt = 0; jt < 4; ++jt)
                acc[it][jt] = __builtin_amdgcn_mfma_f32_16x16x32_bf16(
                    af[it], bf[jt], acc[it][jt], 0, 0, 0);
        __syncthreads();
    }

    // epilogue: val = gemm + bias + residual; per-row LN over 128 cols
    float psum[2][4] = {}, psq[2][4] = {};
#pragma unroll
    for (int it = 0; it < 2; ++it)
#pragma unroll
        for (int jt = 0; jt < 4; ++jt) {
            int col = wc * 64 + jt * 16 + lm;
            float bb = bias[col];
#pragma unroll
            for (int r = 0; r < 4; ++r) {
                int row = row0 + wr * 32 + it * 16 + q * 4 + r;
                float v = acc[it][jt][r] + bb + h[(size_t)row * HID + col];
                acc[it][jt][r] = v;
                psum[it][r] += v;
                psq[it][r] += v * v;
            }
        }
#pragma unroll
    for (int it = 0; it < 2; ++it)
#pragma unroll
        for (int r = 0; r < 4; ++r) {
            float s = psum[it][r], ss = psq[it][r];
#pragma unroll
            for (int k = 1; k < 16; k <<= 1) {
                s += __shfl_xor(s, k, 16);
                ss += __shfl_xor(ss, k, 16);
            }
            psum[it][r] = s;
            psq[it][r] = ss;
        }
    if (lm == 0) {
#pragma unroll
        for (int it = 0; it < 2; ++it)
#pragma unroll
            for (int r = 0; r < 4; ++r) {
                int rl = wr * 32 + it * 16 + q * 4 + r;
                redS[rl * 2 + wc] = psum[it][r];
                redQ[rl * 2 + wc] = psq[it][r];
            }
    }
    __syncthreads();
#pragma unroll
    for (int it = 0; it < 2; ++it)
#pragma unroll
        for (int r = 0; r < 4; ++r) {
            int rl = wr * 32 + it * 16 + q * 4 + r;
            float tot = redS[rl * 2] + redS[rl * 2 + 1];
            float totq = redQ[rl * 2] + redQ[rl * 2 + 1];
            float mu = tot * (1.f / HID);
            float var = totq * (1.f / HID) - mu * mu;
            float rstd = rsqrtf(var + 1e-5f);
            int row = row0 + rl;
#pragma unroll
            for (int jt = 0; jt < 4; ++jt) {
                int col = wc * 64 + jt * 16 + lm;
                float o = (acc[it][jt][r] - mu) * rstd * g[col] + b[col];
                h[(size_t)row * HID + col] = o;
                hb[(size_t)row * HID + col] = f2bf(o);
            }
        }
}

// ---------------- edge attention: 4 nodes/block (1 wave each), 2-way edge unroll ----------------

__global__ __launch_bounds__(256) void attn_kernel(const ushort* __restrict__ qkv,
                                                   const int* __restrict__ ps,
                                                   const float* __restrict__ pea,
                                                   const int* __restrict__ offs,
                                                   const float* __restrict__ We,
                                                   const float* __restrict__ be,
                                                   ushort* __restrict__ attnb) {
    __shared__ float WeS[640], beS[128];
    int t = threadIdx.x;
    for (int idx = t; idx < 640; idx += 256) WeS[idx] = We[idx];
    if (t < 128) beS[t] = be[t];
    __syncthreads();
    int i = blockIdx.x * 4 + (t >> 6);
    int lane = t & 63;
    const int c0 = lane * 2, c1 = c0 + 1;
    const ushort* qrow = qkv + (size_t)i * 384;
    float q0 = bf2f(qrow[c0]), q1 = bf2f(qrow[c1]);
    float bc0 = beS[c0], bc1 = beS[c1];
    float w00 = WeS[c0], w10 = WeS[128 + c0], w20 = WeS[256 + c0],
          w30 = WeS[384 + c0], w40 = WeS[512 + c0];
    float w01 = WeS[c1], w11 = WeS[128 + c1], w21 = WeS[256 + c1],
          w31 = WeS[384 + c1], w41 = WeS[512 + c1];
    float mA = -INFINITY, sA = 0.f, aA0 = 0.f, aA1 = 0.f;
    float mB = -INFINITY, sB = 0.f, aB0 = 0.f, aB1 = 0.f;
    int beg = offs[i], end = offs[i + 1];
    const float scale = 0.17677669529663687f;   // 1/sqrt(32)

    auto step = [&](int p, float& m, float& ss, float& a0, float& a1) {
        int s = ps[p];
        const float* eap = pea + (size_t)p * 5;
        float x0 = eap[0], x1 = eap[1], x2 = eap[2], x3 = eap[3], x4 = eap[4];
        float e0 = bc0 + x0 * w00 + x1 * w10 + x2 * w20 + x3 * w30 + x4 * w40;
        float e1 = bc1 + x0 * w01 + x1 * w11 + x2 * w21 + x3 * w31 + x4 * w41;
        const ushort* srow = qkv + (size_t)s * 384;
        float k0 = bf2f(srow[128 + c0]) + e0, k1 = bf2f(srow[128 + c1]) + e1;
        float part = q0 * k0 + q1 * k1;
        part += __shfl_xor(part, 1, 16);
        part += __shfl_xor(part, 2, 16);
        part += __shfl_xor(part, 4, 16);
        part += __shfl_xor(part, 8, 16);
        float logit = part * scale;
        float nm = fmaxf(m, logit);
        float al = __expf(m - nm);
        float pe = __expf(logit - nm);
        float v0 = bf2f(srow[256 + c0]) + e0, v1 = bf2f(srow[256 + c1]) + e1;
        ss = ss * al + pe;
        a0 = a0 * al + pe * v0;
        a1 = a1 * al + pe * v1;
        m = nm;
    };

    int p = beg;
    for (; p + 1 < end; p += 2) {
        step(p, mA, sA, aA0, aA1);
        step(p + 1, mB, sB, aB0, aB1);
    }
    if (p < end) step(p, mA, sA, aA0, aA1);
    if (mB != -INFINITY) {   // merge state B into A (flash-merge)
        float nm = fmaxf(mA, mB);
        float cA = __expf(mA - nm), cB = __expf(mB - nm);
        sA = sA * cA + sB * cB;
        aA0 = aA0 * cA + aB0 * cB;
        aA1 = aA1 * cA + aB1 * cB;
    }
    float inv = 1.f / fmaxf(sA, 1e-9f);
    attnb[(size_t)i * HID + c0] = f2bf(aA0 * inv);
    attnb[(size_t)i * HID + c1] = f2bf(aA1 * inv);
}

// ---------------- pooling via group-CSR: one block per group, no atomics; ge fused ----------------

__global__ __launch_bounds__(128) void pool_group(const float* __restrict__ h,
                                                  const float* __restrict__ x,
                                                  const int* __restrict__ hlist,
                                                  const int* __restrict__ offs2,
                                                  ushort* __restrict__ geb) {
    int g = blockIdx.x, c = threadIdx.x;   // 128
    int beg = offs2[g], end = offs2[g + 1];
    float mx = -INFINITY, sx = 0.f, sy = 0.f, cx = 0.f, cy = 0.f;
    for (int p = beg; p < end; ++p) {
        int i = hlist[p];
        float hv = h[(size_t)i * HID + c];
        mx = fmaxf(mx, hv);
        int view = (int)x[i * 25 + 3];
        if (view == 0) { sx += hv; cx += 1.f; }
        else if (view == 1) { sy += hv; cy += 1.f; }
    }
    float gm = (end > beg) ? mx : 0.f;
    float px = sx / fmaxf(cx, 1.f), py = sy / fmaxf(cy, 1.f);
    float hx = cx > 0.f ? 1.f : 0.f, hy = cy > 0.f ? 1.f : 0.f;
    float sf = px * hx + py * hy;
    float valid = fmaxf(hx + hy, 1.f);
    geb[g * 256 + c] = f2bf(sf / valid);
    geb[g * 256 + 128 + c] = f2bf(gm);
}

// ---------------- fused pairwise score + symmetrize + sigmoid + mask ----------------
// upper-triangle blocks compute both (i,j) and (j,i) orientations.

__global__ __launch_bounds__(256) void score_final(const ushort* __restrict__ Cab,
                                                   const float* __restrict__ W2,
                                                   const float* __restrict__ b1v,
                                                   const float* __restrict__ b2,
                                                   const int* __restrict__ ev,
                                                   float* __restrict__ out) {
    int bi = blockIdx.y, bj = blockIdx.x;
    if (bj < bi) return;
    __shared__ float Ai[16][129], Bi[16][129], Aj[16][129], Bj[16][129];
    __shared__ float w2s[128], b1s[128];
    int t = threadIdx.y * 16 + threadIdx.x;
    int i0 = bi * 16, j0 = bj * 16;
    for (int idx = t; idx < 2048; idx += 256) {
        int r = idx >> 7, k = idx & 127;
        Ai[r][k] = bf2f(Cab[(size_t)(i0 + r) * 256 + k]);
        Bi[r][k] = bf2f(Cab[(size_t)(i0 + r) * 256 + 128 + k]);
        Aj[r][k] = bf2f(Cab[(size_t)(j0 + r) * 256 + k]);
        Bj[r][k] = bf2f(Cab[(size_t)(j0 + r) * 256 + 128 + k]);
    }
    if (t < 128) { w2s[t] = W2[t]; b1s[t] = b1v[t]; }
    __syncthreads();
    int tx = threadIdx.x, ty = threadIdx.y;
    float sij = 0.f, sji = 0.f;
#pragma unroll 4
    for (int k = 0; k < 128; ++k) {
        float pb = b1s[k], wk = w2s[k];
        sij += fmaxf(Ai[ty][k] + Bj[tx][k] + pb, 0.f) * wk;
        sji += fmaxf(Aj[tx][k] + Bi[ty][k] + pb, 0.f) * wk;
    }
    float z = 0.5f * (sij + sji) + b2[0];
    float sg = 1.f / (1.f + __expf(-z));
    int gi = i0 + ty, gj = j0 + tx;
    float res = (ev[gi] == ev[gj]) ? sg : 0.f;
    out[(size_t)gi * NGROUPS + gj] = res;
    out[(size_t)gj * NGROUPS + gi] = res;
}

// ---------------- launch ----------------

static inline char* align256(char* p) {
    return (char*)(((uintptr_t)p + 255) & ~(uintptr_t)255);
}

extern "C" void kernel_launch(void* const* d_in, const int* in_sizes, int n_in,
                              void* d_out, int out_size, void* d_ws, size_t ws_size,
                              hipStream_t stream) {
    const float* x    = (const float*)d_in[0];
    const int* eidx   = (const int*)d_in[1];
    const float* ea   = (const float*)d_in[2];
    const int* gidx   = (const int*)d_in[3];
    const int* ev     = (const int*)d_in[4];
    const float* embW = (const float*)d_in[5];
    const float* embB = (const float*)d_in[6];
    const float* Wqkv = (const float*)d_in[7];
    const float* bqkv = (const float*)d_in[8];
    const float* We   = (const float*)d_in[9];
    const float* be   = (const float*)d_in[10];
    const float* Wo   = (const float*)d_in[11];
    const float* bo   = (const float*)d_in[12];
    const float* ln1g = (const float*)d_in[13];
    const float* ln1b = (const float*)d_in[14];
    const float* W1   = (const float*)d_in[15];
    const float* b1   = (const float*)d_in[16];
    const float* W2   = (const float*)d_in[17];
    const float* b2   = (const float*)d_in[18];
    const float* ln2g = (const float*)d_in[19];
    const float* ln2b = (const float*)d_in[20];
    const float* affW1 = (const float*)d_in[21];
    const float* affb1 = (const float*)d_in[22];
    const float* affW2 = (const float*)d_in[23];
    const float* affb2 = (const float*)d_in[24];

    const int* src = eidx;
    const int* dst = eidx + NEDGES;

    char* p = (char*)d_ws;
    float* h    = (float*)p;            p += (size_t)NHITS * HID * 4;
    float* pea  = (float*)p;            p += (size_t)NEDGES * 5 * 4;
    int* cnt    = (int*)p;              p += NHITS * 4;        // ┐ contiguous:
    int* cur    = (int*)p;              p += NHITS * 4;        // │ one memset
    int* cnt2   = (int*)p;              p += NGROUPS * 4;      // │
    int* cur2   = (int*)p;              p += NGROUPS * 4;      // ┘
    int* offs   = (int*)p;              p += (NHITS + 1) * 4;
    int* offs2  = (int*)p;              p += (NGROUPS + 1) * 4;
    int* ps     = (int*)p;              p += NEDGES * 4;
    int* hlist  = (int*)p;              p += NHITS * 4;
    p = align256(p);
    ushort* hb    = (ushort*)p;         p += (size_t)NHITS * HID * 2;
    ushort* qkvb  = (ushort*)p;         p += (size_t)NHITS * 384 * 2;
    ushort* attnb = (ushort*)p;         p += (size_t)NHITS * HID * 2;
    ushort* midb  = (ushort*)p;         p += (size_t)NHITS * FFND * 2;
    ushort* geb   = (ushort*)p;         p += (size_t)NGROUPS * 256 * 2;
    ushort* Cab   = (ushort*)p;         p += (size_t)NGROUPS * 256 * 2;
    p = align256(p);
    ushort* Wqkvt = (ushort*)p;         p += (size_t)LAYERS * 384 * HID * 2;
    ushort* Wot   = (ushort*)p;         p += (size_t)LAYERS * HID * HID * 2;
    ushort* W1t   = (ushort*)p;         p += (size_t)LAYERS * FFND * HID * 2;
    ushort* W2t   = (ushort*)p;         p += (size_t)LAYERS * HID * FFND * 2;
    ushort* W1abt = (ushort*)p;         p += (size_t)256 * 256 * 2;

    // --- all weight conversions in ONE launch ---
    TDs tds;
    for (int l = 0; l < LAYERS; ++l) {
        tds.d[l * 4 + 0] = { Wqkv + (size_t)l * HID * 384, Wqkvt + (size_t)l * 384 * HID, HID, 384 };
        tds.d[l * 4 + 1] = { Wo + (size_t)l * HID * HID,   Wot + (size_t)l * HID * HID,   HID, HID };
        tds.d[l * 4 + 2] = { W1 + (size_t)l * HID * FFND,  W1t + (size_t)l * FFND * HID,  HID, FFND };
        tds.d[l * 4 + 3] = { W2 + (size_t)l * FFND * HID,  W2t + (size_t)l * HID * FFND,  FFND, HID };
    }
    tds.d[12] = { affW1,             W1abt,             256, HID };   // W1a -> cols 0..127
    tds.d[13] = { affW1 + 256 * HID, W1abt + 128 * 256, 256, HID };   // W1b -> cols 128..255
    transpose_all<<<dim3(64, 14), 256, 0, stream>>>(tds);

    // --- CSR build (edges->dst; hits->group), one memset for all counters ---
    hipMemsetAsync(cnt, 0, (2 * NHITS + 2 * NGROUPS) * sizeof(int), stream);
    count_kernel<<<NEDGES / 256, 256, 0, stream>>>(dst, gidx, cnt, cnt2);
    scan_kernel<<<1, 256, 0, stream>>>(cnt, offs, cnt2, offs2);
    scatter_kernel<<<NEDGES / 256, 256, 0, stream>>>(src, dst, ea, gidx, offs, cur,
                                                     ps, pea, offs2, cur2, hlist);

    // --- embed ---
    embed_kernel<<<NHITS, 128, 0, stream>>>(x, embW, embB, h, hb);

    // --- transformer layers ---
    for (int l = 0; l < LAYERS; ++l) {
        gemm_mfma<<<dim3(3, NHITS / 128), 256, 0, stream>>>(
            hb, Wqkvt + (size_t)l * 384 * HID, bqkv + l * 384, qkvb, NHITS, 384, HID, 0);
        attn_kernel<<<NHITS / 4, 256, 0, stream>>>(qkvb, ps, pea, offs,
                                                   We + (size_t)l * 5 * HID, be + l * HID, attnb);
        gemm_ln<<<NHITS / 64, 256, 0, stream>>>(
            attnb, Wot + (size_t)l * HID * HID, bo + l * HID,
            ln1g + l * HID, ln1b + l * HID, h, hb, HID);
        gemm_mfma<<<dim3(4, NHITS / 128), 256, 0, stream>>>(
            hb, W1t + (size_t)l * FFND * HID, b1 + l * FFND, midb, NHITS, FFND, HID, 1);
        gemm_ln<<<NHITS / 64, 256, 0, stream>>>(
            midb, W2t + (size_t)l * HID * FFND, b2 + l * HID,
            ln2g + l * HID, ln2b + l * HID, h, hb, FFND);
    }

    // --- pooling (group-CSR, no atomics, ge fused) ---
    pool_group<<<NGROUPS, 128, 0, stream>>>(h, x, hlist, offs2, geb);

    // --- affinity head: one GEMM (A|B concat), fused score+symmetrize+sigmoid ---
    gemm_mfma<<<dim3(2, NGROUPS / 128), 256, 0, stream>>>(
        geb, W1abt, nullptr, Cab, NGROUPS, 256, 256, 0);
    score_final<<<dim3(NGROUPS / 16, NGROUPS / 16), dim3(16, 16), 0, stream>>>(
        Cab, affW2, affb1, affb2, ev, (float*)d_out);
}